// Round 1
// baseline (1092.102 us; speedup 1.0000x reference)
//
#include <hip/hip_runtime.h>
#include <math.h>

#define NN 10000
#define NE 160000

namespace {
// MP_PATHS in reference order
constexpr int kL1[11] = {0,0,0,1,1,1,1,2,2,2,2};
constexpr int kL2[11] = {0,1,2,0,1,1,2,0,1,2,2};
constexpr int kL3[11] = {0,1,2,1,0,2,1,2,1,0,2};
// TD_PATHS in reference order
constexpr int tL1[7] = {0,0,1,1,1,2,2};
constexpr int tL2[7] = {0,1,0,1,2,1,2};
constexpr int tL3[7] = {0,1,1,0,1,1,0};
constexpr int kOFF[3] = {0,1,4};
constexpr int kWID[3] = {1,3,5};
}

__device__ float GAUNT_d[729];
__device__ unsigned char CT_P_d[115], CT_R_d[115], CT_L2_d[115];

// float32 spherical harmonics component (matches reference _sph_harm numerics)
__device__ __forceinline__ float sphf(int c, float x, float y, float z) {
  const float s3 = 1.7320508075688772f;
  switch (c) {
    case 0: return 1.0f;
    case 1: return x;
    case 2: return y;
    case 3: return z;
    case 4: return s3 * x * y;
    case 5: return s3 * y * z;
    case 6: return 0.5f * (3.0f * z * z - 1.0f);
    case 7: return s3 * x * z;
    default: return 0.5f * s3 * (x * x - y * y);
  }
}

__global__ void gaunt_kernel() {
  const int idx = threadIdx.x;
  const double T[8] = {-0.9602898564975363, -0.7966664774136267, -0.5255324099163290, -0.1834346424956498,
                        0.1834346424956498,  0.5255324099163290,  0.7966664774136267,  0.9602898564975363};
  const double Wq[8] = {0.1012285362903763, 0.2223810344533745, 0.3137066458778873, 0.3626837833783620,
                        0.3626837833783620, 0.3137066458778873, 0.2223810344533745, 0.1012285362903763};
  if (idx < 729) {
    int p = idx / 81, q = (idx / 9) % 9, r = idx % 9;
    double acc = 0.0;
    #pragma unroll
    for (int it = 0; it < 8; ++it) {
      double st = sqrt(1.0 - T[it] * T[it]);
      for (int ip = 0; ip < 16; ++ip) {
        double phi = (double)ip * (6.283185307179586 / 16.0);
        float xf = (float)(st * cos(phi));
        float yf = (float)(st * sin(phi));
        float zf = (float)T[it];
        acc += (Wq[it] / 32.0) * (double)sphf(p, xf, yf, zf) * (double)sphf(q, xf, yf, zf) * (double)sphf(r, xf, yf, zf);
      }
    }
    GAUNT_d[idx] = (fabs(acc) < 1e-10) ? 0.0f : (float)acc;
  }
  if (idx == 0) {
    // coef index -> (p_global, r_global, l2) tables, in (path, i, k) nesting order
    int c = 0;
    for (int t = 0; t < 11; ++t) {
      int l1 = kL1[t], l2 = kL2[t], l3 = kL3[t];
      for (int i = 0; i < kWID[l1]; ++i)
        for (int k = 0; k < kWID[l3]; ++k) {
          CT_P_d[c]  = (unsigned char)(kOFF[l1] + i);
          CT_R_d[c]  = (unsigned char)(kOFF[l3] + k);
          CT_L2_d[c] = (unsigned char)l2;
          ++c;
        }
    }
  }
}

// ---- destination-sorted CSR build ----
__global__ void zero_kernel(int* __restrict__ cnt) {
  int i = blockIdx.x * 256 + threadIdx.x;
  if (i < NN) cnt[i] = 0;
}

__global__ void hist_kernel(const int* __restrict__ dstI, int* __restrict__ cnt) {
  int e = blockIdx.x * 256 + threadIdx.x;
  if (e < NE) atomicAdd(&cnt[dstI[e]], 1);
}

// single-block exclusive scan over cnt(=wofs) -> rowptr; wofs rewritten to start offsets
__global__ void scan_kernel(int* __restrict__ wofs, int* __restrict__ rowptr) {
  __shared__ int partial[1024];
  const int tid = threadIdx.x;           // 1024 threads, 10 elements each
  const int base = tid * 10;
  int local[10];
  int s = 0;
  #pragma unroll
  for (int i = 0; i < 10; ++i) {
    int idx = base + i;
    int v = (idx < NN) ? wofs[idx] : 0;
    local[i] = s;                        // exclusive within chunk
    s += v;
  }
  partial[tid] = s;
  __syncthreads();
  for (int off = 1; off < 1024; off <<= 1) {
    int v = (tid >= off) ? partial[tid - off] : 0;
    __syncthreads();
    partial[tid] += v;
    __syncthreads();
  }
  int pre = (tid == 0) ? 0 : partial[tid - 1];
  #pragma unroll
  for (int i = 0; i < 10; ++i) {
    int idx = base + i;
    if (idx < NN) {
      int v = pre + local[i];
      rowptr[idx] = v;
      wofs[idx] = v;
    }
  }
  if (tid == 0) rowptr[NN] = NE;
}

// edge basis, scattered directly into dst-sorted slot order
__global__ void edge_kernel(const float* __restrict__ pos,
                            const int* __restrict__ srcI, const int* __restrict__ dstI,
                            int* __restrict__ wofs, int* __restrict__ ssrc,
                            float* __restrict__ Yb, float* __restrict__ Rb) {
  int e = blockIdx.x * 256 + threadIdx.x;
  if (e >= NE) return;
  int s = srcI[e], d = dstI[e];
  float dx = pos[s * 3 + 0] - pos[d * 3 + 0];
  float dy = pos[s * 3 + 1] - pos[d * 3 + 1];
  float dz = pos[s * 3 + 2] - pos[d * 3 + 2];
  float r2 = dx * dx + dy * dy + dz * dz;
  float r = sqrtf(fmaxf(r2, 1e-12f));
  float inv = 1.0f / r;
  float x = dx * inv, y = dy * inv, z = dz * inv;
  const float s3 = 1.7320508075688772f;
  int sp = atomicAdd(&wofs[d], 1);       // dst-sorted slot
  ssrc[sp] = s;
  Yb[sp * 9 + 0] = 1.0f;
  Yb[sp * 9 + 1] = x;
  Yb[sp * 9 + 2] = y;
  Yb[sp * 9 + 3] = z;
  Yb[sp * 9 + 4] = s3 * x * y;
  Yb[sp * 9 + 5] = s3 * y * z;
  Yb[sp * 9 + 6] = 0.5f * (3.0f * z * z - 1.0f);
  Yb[sp * 9 + 7] = s3 * x * z;
  Yb[sp * 9 + 8] = 0.5f * s3 * (x * x - y * y);
  float rc = fminf(r, 5.0f - 1e-6f);
  float cut = (r < 5.0f) ? expf(-(rc * rc) / ((5.0f - rc) * (5.0f + rc))) : 0.0f;
  float yv = 1.0f / (1.0f + r);
  float om = 1.0f - yv;
  const float binom[8] = {1.f, 7.f, 21.f, 35.f, 35.f, 21.f, 7.f, 1.f};
  float yk[8], ok[8];
  yk[0] = 1.0f; ok[0] = 1.0f;
  #pragma unroll
  for (int k = 1; k < 8; ++k) { yk[k] = yk[k - 1] * yv; ok[k] = ok[k - 1] * om; }
  #pragma unroll
  for (int k = 0; k < 8; ++k) Rb[sp * 8 + k] = binom[k] * yk[k] * ok[7 - k] * cut;
}

__global__ void init_kernel(const float* __restrict__ embed, const int* __restrict__ Z,
                            float* __restrict__ xb) {
  int idx = blockIdx.x * 256 + threadIdx.x;
  if (idx >= NN * 288) return;
  int n = idx / 288;
  int rem = idx - n * 288;
  int p = rem >> 5, f = rem & 31;
  xb[idx] = (p == 0) ? embed[Z[n] * 32 + f] : 0.0f;
}

// fused: gather-based message pass (no atomics) + dense1 + silu_e3 + dense2 + residual
// one block (288 threads) per destination node; tid = p*32+f
__launch_bounds__(288)
__global__ void node_kernel(const float* __restrict__ xin, float* __restrict__ xout,
                            const float* __restrict__ Yb, const float* __restrict__ Rb,
                            const float* __restrict__ Wg,
                            const float* __restrict__ W1, const float* __restrict__ b1,
                            const float* __restrict__ W2, const float* __restrict__ b2,
                            const int* __restrict__ rowptr, const int* __restrict__ ssrc) {
  __shared__ float Gs[729];
  __shared__ float Ws[11 * 256];
  __shared__ unsigned char Tp[115], Tr[115], Tl2[115];
  __shared__ float Ys[9][9];
  __shared__ float Rs[9][8];
  __shared__ int   Es[9];
  __shared__ float Cs[9][115];
  __shared__ float red[9][288];   // slot-partial reduce; later reused as yn
  __shared__ float act[288];
  __shared__ float sb[32];

  const int n = blockIdx.x;
  const int tid = threadIdx.x;
  const int p = tid >> 5, f = tid & 31;

  for (int i = tid; i < 729; i += 288) Gs[i] = GAUNT_d[i];
  for (int i = tid; i < 115; i += 288) { Tp[i] = CT_P_d[i]; Tr[i] = CT_R_d[i]; Tl2[i] = CT_L2_d[i]; }
  if (tid < 256) {
    #pragma unroll
    for (int t = 0; t < 11; ++t) {
      const int off = ((kL1[t] * 3 + kL2[t]) * 3 + kL3[t]) * 256;  // compile-time
      Ws[t * 256 + tid] = Wg[off + tid];
    }
  }

  const int r0 = rowptr[n];
  const int nE = rowptr[n + 1] - r0;
  const float xreg = xin[n * 288 + tid];

  float macc[9] = {0.f, 0.f, 0.f, 0.f, 0.f, 0.f, 0.f, 0.f, 0.f};

  for (int base = 0; base < nE; base += 9) {
    __syncthreads();   // also covers initial Gs/Ws loads; protects Ys/Rs/Es/Cs reuse
    if (tid < 162) {
      int le = tid / 18, j = tid - le * 18;
      int idx = base + le;
      bool valid = idx < nE;
      int e = r0 + (valid ? idx : 0);
      if (j < 9)        Ys[le][j]     = valid ? Yb[e * 9 + j] : 0.0f;
      else if (j < 17)  Rs[le][j - 9] = valid ? Rb[e * 8 + (j - 9)] : 0.0f;
      else              Es[le]        = valid ? ssrc[e] : 0;
    }
    __syncthreads();
    // cooperative per-slot coefficients: coef[c] = sum_q G[p,q,r] * Y[q]
    for (int i = tid; i < 1152; i += 288) {
      int le = i >> 7, c = i & 127;
      if (c < 115) {
        int pp = Tp[c], rr = Tr[c], l2 = Tl2[c];
        int q0 = (l2 == 0) ? 0 : ((l2 == 1) ? 1 : 4);
        int nq = (l2 == 0) ? 1 : ((l2 == 1) ? 3 : 5);
        float a = 0.0f;
        for (int jq = 0; jq < nq; ++jq) a += Gs[(pp * 9 + q0 + jq) * 9 + rr] * Ys[le][q0 + jq];
        Cs[le][c] = a;
      }
    }
    __syncthreads();
    if (base + p < nE) {       // thread's edge slot = p (0..8)
      float rwv[11];
      #pragma unroll
      for (int t = 0; t < 11; ++t) {
        float a = 0.0f;
        #pragma unroll
        for (int k = 0; k < 8; ++k) a += Rs[p][k] * Ws[t * 256 + k * 32 + f];
        rwv[t] = a;
      }
      const int sn = Es[p];
      float xsv[9];
      #pragma unroll
      for (int pp = 0; pp < 9; ++pp) xsv[pp] = xin[sn * 288 + pp * 32 + f];
      int c = 0;
      #pragma unroll
      for (int t = 0; t < 11; ++t) {
        const int o1 = kOFF[kL1[t]], w1 = kWID[kL1[t]];
        const int o3 = kOFF[kL3[t]], w3 = kWID[kL3[t]];
        #pragma unroll
        for (int i = 0; i < w1; ++i) {
          float tv = rwv[t] * xsv[o1 + i];
          #pragma unroll
          for (int k = 0; k < w3; ++k) { macc[o3 + k] += Cs[p][c] * tv; ++c; }
        }
      }
    }
  }

  // reduce 9 slot-partials -> y = x + msg
  __syncthreads();
  #pragma unroll
  for (int rr = 0; rr < 9; ++rr) red[p][rr * 32 + f] = macc[rr];
  __syncthreads();
  float y = xreg;
  #pragma unroll
  for (int pp = 0; pp < 9; ++pp) y += red[pp][tid];
  __syncthreads();
  float* yn = &red[0][0];
  yn[tid] = y;
  __syncthreads();

  // dense1 + silu_e3 + dense2 + residual
  const int dg = (p == 0) ? 0 : ((p < 4) ? 1 : 2);
  float a = (p == 0) ? b1[f] : 0.0f;
  #pragma unroll
  for (int ff = 0; ff < 32; ++ff) a += yn[p * 32 + ff] * W1[(dg * 32 + ff) * 32 + f];
  if (p == 0) sb[f] = a;
  __syncthreads();
  float s = sb[f];
  float sg = 1.0f / (1.0f + expf(-s));
  float v = (p == 0) ? s * sg : a * (sg * (1.0f + s * (1.0f - sg)));
  act[tid] = v;
  __syncthreads();
  float o = (p == 0) ? b2[f] : 0.0f;
  #pragma unroll
  for (int ff = 0; ff < 32; ++ff) o += act[p * 32 + ff] * W2[(dg * 32 + ff) * 32 + f];
  xout[n * 288 + tid] = xreg + o;
}

// tensor_dense + mono/dipo outputs, one block (128 thr) per node; tid = r*32+f, r in 0..3
__global__ void final_kernel(const float* __restrict__ xb, const float* __restrict__ tdW,
                             const float* __restrict__ monoW, const float* __restrict__ ebias,
                             const int* __restrict__ Z, float* __restrict__ out) {
  __shared__ float xl[288];
  __shared__ float B[4][32];
  __shared__ float cb[16];
  const int n = blockIdx.x;
  const int tid = threadIdx.x;
  const int r = tid >> 5, f = tid & 31;
  for (int i = tid; i < 288; i += 128) xl[i] = xb[n * 288 + i];
  __syncthreads();
  float creg = 0.0f;  // c[r][g=f] accumulator, valid on f<4 threads
  #pragma unroll
  for (int t = 0; t < 7; ++t) {
    const int l1 = tL1[t], l2 = tL2[t], l3 = tL3[t];
    const bool active = (l3 == 0) ? (r == 0) : (r >= 1);
    float b = 0.0f;
    if (active) {
      #pragma unroll
      for (int i = 0; i < kWID[l1]; ++i) {
        const int p = kOFF[l1] + i;
        float xp = xl[p * 32 + f];
        #pragma unroll
        for (int j = 0; j < kWID[l2]; ++j) {
          const int q = kOFF[l2] + j;
          b += GAUNT_d[(p * 9 + q) * 9 + r] * xp * xl[q * 32 + f];
        }
      }
    }
    B[r][f] = b;
    __syncthreads();
    if (f < 4 && active) {
      const float* w = tdW + ((l1 * 3 + l2) * 2 + l3) * 128;
      float acc = 0.0f;
      #pragma unroll
      for (int f2 = 0; f2 < 32; ++f2) acc += B[r][f2] * w[f2 * 4 + f];
      creg += acc;
    }
    __syncthreads();
  }
  if (f < 4) cb[r * 4 + f] = creg;
  __syncthreads();
  if (tid < 4) {
    int g = tid;
    float m = 0.0f;
    #pragma unroll
    for (int j = 0; j < 4; ++j) m += cb[j] * monoW[j * 4 + g];
    out[n * 4 + g] = m + ebias[Z[n]];
  }
  if (tid < 12) {
    int row = tid / 4 + 1, g = tid % 4;
    float s = cb[g];
    float gate = (s > -1.0f && s < 1.0f) ? 1.0f : 0.0f;
    out[NN * 4 + n * 12 + (row - 1) * 4 + g] = cb[row * 4 + g] * gate * 0.3f;
  }
}

extern "C" void kernel_launch(void* const* d_in, const int* in_sizes, int n_in,
                              void* d_out, int out_size, void* d_ws, size_t ws_size,
                              hipStream_t stream) {
  const float* positions = (const float*)d_in[0];
  const float* embed     = (const float*)d_in[1];
  const float* mpW       = (const float*)d_in[2];   // (3,3,3,3,8,32)
  const float* d1W       = (const float*)d_in[3];   // (3,3,32,32)
  const float* d1b       = (const float*)d_in[4];   // (3,32)
  const float* d2W       = (const float*)d_in[5];
  const float* d2b       = (const float*)d_in[6];
  const float* tdW       = (const float*)d_in[7];   // (3,3,2,32,4)
  const float* monoW     = (const float*)d_in[8];   // (4,4)
  const float* ebias     = (const float*)d_in[9];   // (18,)
  const int* Z   = (const int*)d_in[10];
  const int* dst = (const int*)d_in[11];
  const int* src = (const int*)d_in[12];
  float* out = (float*)d_out;

  float* Yb = (float*)d_ws;                 // NE*9  (dst-sorted)
  float* Rb = Yb + (size_t)NE * 9;          // NE*8  (dst-sorted)
  float* x0 = Rb + (size_t)NE * 8;          // NN*288
  float* x1 = x0 + (size_t)NN * 288;        // NN*288
  int* ssrc   = (int*)(x1 + (size_t)NN * 288);  // NE   (dst-sorted src ids)
  int* rowptr = ssrc + NE;                  // NN+1
  int* wofs   = rowptr + (NN + 1);          // NN   (hist counters -> scatter cursors)

  gaunt_kernel<<<1, 768, 0, stream>>>();
  zero_kernel<<<(NN + 255) / 256, 256, 0, stream>>>(wofs);
  hist_kernel<<<NE / 256, 256, 0, stream>>>(dst, wofs);
  scan_kernel<<<1, 1024, 0, stream>>>(wofs, rowptr);
  edge_kernel<<<NE / 256, 256, 0, stream>>>(positions, src, dst, wofs, ssrc, Yb, Rb);
  init_kernel<<<(NN * 288 + 255) / 256, 256, 0, stream>>>(embed, Z, x0);

  const float* xi = x0;
  float* xo = x1;
  for (int it = 0; it < 3; ++it) {
    node_kernel<<<NN, 288, 0, stream>>>(xi, xo, Yb, Rb, mpW + (size_t)it * 27 * 256,
                                        d1W + (size_t)it * 3 * 1024, d1b + it * 32,
                                        d2W + (size_t)it * 3 * 1024, d2b + it * 32,
                                        rowptr, ssrc);
    const float* t = xo; xo = (float*)xi; xi = t;
  }
  // after 3 iters (x0->x1->x0->x1), xi points at the final buffer (x1)
  final_kernel<<<NN, 128, 0, stream>>>(xi, tdW, monoW, ebias, Z, out);
}

// Round 2
// 742.389 us; speedup vs baseline: 1.4711x; 1.4711x over previous
//
#include <hip/hip_runtime.h>
#include <math.h>

#define NN 10000
#define NE 160000

namespace {
// MP_PATHS in reference order
constexpr int kL1[11] = {0,0,0,1,1,1,1,2,2,2,2};
constexpr int kL2[11] = {0,1,2,0,1,1,2,0,1,2,2};
constexpr int kL3[11] = {0,1,2,1,0,2,1,2,1,0,2};
// TD_PATHS in reference order
constexpr int tL1[7] = {0,0,1,1,1,2,2};
constexpr int tL2[7] = {0,1,0,1,2,1,2};
constexpr int tL3[7] = {0,1,1,0,1,1,0};
constexpr int kOFF[3] = {0,1,4};
constexpr int kWID[3] = {1,3,5};
}

__device__ float GAUNT_d[729];
__device__ unsigned char CT_P_d[115], CT_R_d[115], CT_L2_d[115];

// float32 spherical harmonics component (matches reference _sph_harm numerics)
__device__ __forceinline__ float sphf(int c, float x, float y, float z) {
  const float s3 = 1.7320508075688772f;
  switch (c) {
    case 0: return 1.0f;
    case 1: return x;
    case 2: return y;
    case 3: return z;
    case 4: return s3 * x * y;
    case 5: return s3 * y * z;
    case 6: return 0.5f * (3.0f * z * z - 1.0f);
    case 7: return s3 * x * z;
    default: return 0.5f * s3 * (x * x - y * y);
  }
}

__global__ void gaunt_kernel() {
  const int idx = threadIdx.x;
  const double T[8] = {-0.9602898564975363, -0.7966664774136267, -0.5255324099163290, -0.1834346424956498,
                        0.1834346424956498,  0.5255324099163290,  0.7966664774136267,  0.9602898564975363};
  const double Wq[8] = {0.1012285362903763, 0.2223810344533745, 0.3137066458778873, 0.3626837833783620,
                        0.3626837833783620, 0.3137066458778873, 0.2223810344533745, 0.1012285362903763};
  if (idx < 729) {
    int p = idx / 81, q = (idx / 9) % 9, r = idx % 9;
    double acc = 0.0;
    #pragma unroll
    for (int it = 0; it < 8; ++it) {
      double st = sqrt(1.0 - T[it] * T[it]);
      for (int ip = 0; ip < 16; ++ip) {
        double phi = (double)ip * (6.283185307179586 / 16.0);
        float xf = (float)(st * cos(phi));
        float yf = (float)(st * sin(phi));
        float zf = (float)T[it];
        acc += (Wq[it] / 32.0) * (double)sphf(p, xf, yf, zf) * (double)sphf(q, xf, yf, zf) * (double)sphf(r, xf, yf, zf);
      }
    }
    GAUNT_d[idx] = (fabs(acc) < 1e-10) ? 0.0f : (float)acc;
  }
  if (idx == 0) {
    // coef index -> (p_global, r_global, l2) tables, in (path, i, k) nesting order
    int c = 0;
    for (int t = 0; t < 11; ++t) {
      int l1 = kL1[t], l2 = kL2[t], l3 = kL3[t];
      for (int i = 0; i < kWID[l1]; ++i)
        for (int k = 0; k < kWID[l3]; ++k) {
          CT_P_d[c]  = (unsigned char)(kOFF[l1] + i);
          CT_R_d[c]  = (unsigned char)(kOFF[l3] + k);
          CT_L2_d[c] = (unsigned char)l2;
          ++c;
        }
    }
  }
}

// ---- destination-sorted edge order build ----
__global__ void zero_kernel(int* __restrict__ cnt) {
  int i = blockIdx.x * 256 + threadIdx.x;
  if (i < NN) cnt[i] = 0;
}

__global__ void hist_kernel(const int* __restrict__ dstI, int* __restrict__ cnt) {
  int e = blockIdx.x * 256 + threadIdx.x;
  if (e < NE) atomicAdd(&cnt[dstI[e]], 1);
}

// single-block in-place exclusive scan over wofs (counts -> start offsets)
__global__ void scan_kernel(int* __restrict__ wofs) {
  __shared__ int partial[1024];
  const int tid = threadIdx.x;           // 1024 threads, 10 elements each
  const int base = tid * 10;
  int local[10];
  int s = 0;
  #pragma unroll
  for (int i = 0; i < 10; ++i) {
    int idx = base + i;
    int v = (idx < NN) ? wofs[idx] : 0;
    local[i] = s;                        // exclusive within chunk
    s += v;
  }
  partial[tid] = s;
  __syncthreads();
  for (int off = 1; off < 1024; off <<= 1) {
    int v = (tid >= off) ? partial[tid - off] : 0;
    __syncthreads();
    partial[tid] += v;
    __syncthreads();
  }
  int pre = (tid == 0) ? 0 : partial[tid - 1];
  #pragma unroll
  for (int i = 0; i < 10; ++i) {
    int idx = base + i;
    if (idx < NN) wofs[idx] = pre + local[i];
  }
}

// edge basis, scattered directly into dst-sorted slot order
__global__ void edge_kernel(const float* __restrict__ pos,
                            const int* __restrict__ srcI, const int* __restrict__ dstI,
                            int* __restrict__ wofs, int* __restrict__ ssrc, int* __restrict__ sdst,
                            float* __restrict__ Yb, float* __restrict__ Rb) {
  int e = blockIdx.x * 256 + threadIdx.x;
  if (e >= NE) return;
  int s = srcI[e], d = dstI[e];
  float dx = pos[s * 3 + 0] - pos[d * 3 + 0];
  float dy = pos[s * 3 + 1] - pos[d * 3 + 1];
  float dz = pos[s * 3 + 2] - pos[d * 3 + 2];
  float r2 = dx * dx + dy * dy + dz * dz;
  float r = sqrtf(fmaxf(r2, 1e-12f));
  float inv = 1.0f / r;
  float x = dx * inv, y = dy * inv, z = dz * inv;
  const float s3 = 1.7320508075688772f;
  int sp = atomicAdd(&wofs[d], 1);       // dst-sorted slot
  ssrc[sp] = s;
  sdst[sp] = d;
  Yb[sp * 9 + 0] = 1.0f;
  Yb[sp * 9 + 1] = x;
  Yb[sp * 9 + 2] = y;
  Yb[sp * 9 + 3] = z;
  Yb[sp * 9 + 4] = s3 * x * y;
  Yb[sp * 9 + 5] = s3 * y * z;
  Yb[sp * 9 + 6] = 0.5f * (3.0f * z * z - 1.0f);
  Yb[sp * 9 + 7] = s3 * x * z;
  Yb[sp * 9 + 8] = 0.5f * s3 * (x * x - y * y);
  float rc = fminf(r, 5.0f - 1e-6f);
  float cut = (r < 5.0f) ? expf(-(rc * rc) / ((5.0f - rc) * (5.0f + rc))) : 0.0f;
  float yv = 1.0f / (1.0f + r);
  float om = 1.0f - yv;
  const float binom[8] = {1.f, 7.f, 21.f, 35.f, 35.f, 21.f, 7.f, 1.f};
  float yk[8], ok[8];
  yk[0] = 1.0f; ok[0] = 1.0f;
  #pragma unroll
  for (int k = 1; k < 8; ++k) { yk[k] = yk[k - 1] * yv; ok[k] = ok[k - 1] * om; }
  #pragma unroll
  for (int k = 0; k < 8; ++k) Rb[sp * 8 + k] = binom[k] * yk[k] * ok[7 - k] * cut;
}

__global__ void init_kernel(const float* __restrict__ embed, const int* __restrict__ Z,
                            float* __restrict__ xb) {
  int idx = blockIdx.x * 256 + threadIdx.x;
  if (idx >= NN * 288) return;
  int n = idx / 288;
  int rem = idx - n * 288;
  int p = rem >> 5, f = rem & 31;
  xb[idx] = (p == 0) ? embed[Z[n] * 32 + f] : 0.0f;
}

// edge-major message pass over dst-sorted edges; block-level segmented reduction
// cuts atomics from 1/edge-element to 1/(block,distinct-dst)-element (~5x fewer)
__launch_bounds__(256)
__global__ void message_kernel(const float* __restrict__ xb, float* __restrict__ yb,
                               const float* __restrict__ Yb, const float* __restrict__ Rb,
                               const float* __restrict__ Wg,
                               const int* __restrict__ ssrc, const int* __restrict__ sdst) {
  __shared__ float Gs[729];
  __shared__ float Ws[11 * 256];
  __shared__ float Ys[8][9];
  __shared__ float Rs[8][8];
  __shared__ float Cs[8][115];
  __shared__ float Ms[8][288];
  __shared__ int Ds[8];
  __shared__ int Hs[9];
  __shared__ int nseg_s;
  __shared__ unsigned char Tp[115], Tr[115], Tl2[115];
  const int tid = threadIdx.x;
  const int e0 = blockIdx.x * 8;

  for (int i = tid; i < 729; i += 256) Gs[i] = GAUNT_d[i];
  for (int i = tid; i < 115; i += 256) { Tp[i] = CT_P_d[i]; Tr[i] = CT_R_d[i]; Tl2[i] = CT_L2_d[i]; }
  #pragma unroll
  for (int t = 0; t < 11; ++t) {
    const int off = ((kL1[t] * 3 + kL2[t]) * 3 + kL3[t]) * 256;  // compile-time
    Ws[t * 256 + tid] = Wg[off + tid];
  }
  for (int i = tid; i < 128; i += 256) {
    int le = i >> 4, q = i & 15;
    if (q < 9) Ys[le][q] = Yb[(e0 + le) * 9 + q];
  }
  for (int i = tid; i < 64; i += 256) Rs[i >> 3][i & 7] = Rb[e0 * 8 + i];
  if (tid < 8) Ds[tid] = sdst[e0 + tid];
  __syncthreads();

  // cooperative per-edge coefficients: coef[c] = sum_q G[p, q, r] * Y[q]
  for (int i = tid; i < 1024; i += 256) {
    int le = i >> 7, c = i & 127;
    if (c < 115) {
      int p = Tp[c], r = Tr[c], l2 = Tl2[c];
      int q0 = (l2 == 0) ? 0 : ((l2 == 1) ? 1 : 4);
      int nq = (l2 == 0) ? 1 : ((l2 == 1) ? 3 : 5);
      float a = 0.0f;
      for (int j = 0; j < nq; ++j) a += Gs[(p * 9 + q0 + j) * 9 + r] * Ys[le][q0 + j];
      Cs[le][c] = a;
    }
  }
  if (tid == 0) {
    // segment heads among the 8 sorted edges
    int ns = 0;
    #pragma unroll
    for (int i = 0; i < 8; ++i)
      if (i == 0 || Ds[i] != Ds[i - 1]) Hs[ns++] = i;
    Hs[ns] = 8;
    nseg_s = ns;
  }
  __syncthreads();

  const int le = tid >> 5, f = tid & 31;
  const int sn = ssrc[e0 + le];

  float rw[11];
  #pragma unroll
  for (int t = 0; t < 11; ++t) {
    float a = 0.0f;
    #pragma unroll
    for (int k = 0; k < 8; ++k) a += Rs[le][k] * Ws[t * 256 + k * 32 + f];
    rw[t] = a;
  }
  float xs[9];
  #pragma unroll
  for (int p = 0; p < 9; ++p) xs[p] = xb[sn * 288 + p * 32 + f];

  float msg[9] = {0.f, 0.f, 0.f, 0.f, 0.f, 0.f, 0.f, 0.f, 0.f};
  int c = 0;
  #pragma unroll
  for (int t = 0; t < 11; ++t) {
    const int o1 = kOFF[kL1[t]], w1 = kWID[kL1[t]];
    const int o3 = kOFF[kL3[t]], w3 = kWID[kL3[t]];
    #pragma unroll
    for (int i = 0; i < w1; ++i) {
      float tv = rw[t] * xs[o1 + i];
      #pragma unroll
      for (int k = 0; k < w3; ++k) { msg[o3 + k] += Cs[le][c] * tv; ++c; }
    }
  }
  #pragma unroll
  for (int rr = 0; rr < 9; ++rr) Ms[le][rr * 32 + f] = msg[rr];
  __syncthreads();

  // segmented reduction over the (sorted) 8 edges; one atomic per segment-element
  const int nseg = nseg_s;
  for (int i = tid; i < nseg * 288; i += 256) {
    int s = i / 288, rf = i - s * 288;
    int h = Hs[s], hend = Hs[s + 1];
    float a = 0.0f;
    for (int e = h; e < hend; ++e) a += Ms[e][rf];
    atomicAdd(&yb[Ds[h] * 288 + rf], a);
  }
}

// fused dense1 + silu_e3 + dense2 + residual, one block per node
__global__ void dense_kernel(const float* __restrict__ ybuf, float* __restrict__ xb,
                             const float* __restrict__ W1, const float* __restrict__ b1,
                             const float* __restrict__ W2, const float* __restrict__ b2) {
  __shared__ float yn[288];
  __shared__ float act[288];
  __shared__ float sb[32];
  const int n = blockIdx.x;
  const int tid = threadIdx.x;  // p*32+g, 288 threads
  const int p = tid >> 5, g = tid & 31;
  yn[tid] = ybuf[n * 288 + tid];
  __syncthreads();
  const int dg = (p == 0) ? 0 : ((p < 4) ? 1 : 2);
  float a = (p == 0) ? b1[g] : 0.0f;
  #pragma unroll
  for (int f = 0; f < 32; ++f) a += yn[p * 32 + f] * W1[(dg * 32 + f) * 32 + g];
  if (p == 0) sb[g] = a;
  __syncthreads();
  float s = sb[g];
  float sg = 1.0f / (1.0f + expf(-s));
  float v = (p == 0) ? s * sg : a * (sg * (1.0f + s * (1.0f - sg)));
  act[tid] = v;
  __syncthreads();
  float o = (p == 0) ? b2[g] : 0.0f;
  #pragma unroll
  for (int f = 0; f < 32; ++f) o += act[p * 32 + f] * W2[(dg * 32 + f) * 32 + g];
  xb[n * 288 + tid] += o;
}

// tensor_dense + mono/dipo outputs, one block (128 thr) per node; tid = r*32+f, r in 0..3
__global__ void final_kernel(const float* __restrict__ xb, const float* __restrict__ tdW,
                             const float* __restrict__ monoW, const float* __restrict__ ebias,
                             const int* __restrict__ Z, float* __restrict__ out) {
  __shared__ float xl[288];
  __shared__ float B[4][32];
  __shared__ float cb[16];
  const int n = blockIdx.x;
  const int tid = threadIdx.x;
  const int r = tid >> 5, f = tid & 31;
  for (int i = tid; i < 288; i += 128) xl[i] = xb[n * 288 + i];
  __syncthreads();
  float creg = 0.0f;  // c[r][g=f] accumulator, valid on f<4 threads
  #pragma unroll
  for (int t = 0; t < 7; ++t) {
    const int l1 = tL1[t], l2 = tL2[t], l3 = tL3[t];
    const bool active = (l3 == 0) ? (r == 0) : (r >= 1);
    float b = 0.0f;
    if (active) {
      #pragma unroll
      for (int i = 0; i < kWID[l1]; ++i) {
        const int p = kOFF[l1] + i;
        float xp = xl[p * 32 + f];
        #pragma unroll
        for (int j = 0; j < kWID[l2]; ++j) {
          const int q = kOFF[l2] + j;
          b += GAUNT_d[(p * 9 + q) * 9 + r] * xp * xl[q * 32 + f];
        }
      }
    }
    B[r][f] = b;
    __syncthreads();
    if (f < 4 && active) {
      const float* w = tdW + ((l1 * 3 + l2) * 2 + l3) * 128;
      float acc = 0.0f;
      #pragma unroll
      for (int f2 = 0; f2 < 32; ++f2) acc += B[r][f2] * w[f2 * 4 + f];
      creg += acc;
    }
    __syncthreads();
  }
  if (f < 4) cb[r * 4 + f] = creg;
  __syncthreads();
  if (tid < 4) {
    int g = tid;
    float m = 0.0f;
    #pragma unroll
    for (int j = 0; j < 4; ++j) m += cb[j] * monoW[j * 4 + g];
    out[n * 4 + g] = m + ebias[Z[n]];
  }
  if (tid < 12) {
    int row = tid / 4 + 1, g = tid % 4;
    float s = cb[g];
    float gate = (s > -1.0f && s < 1.0f) ? 1.0f : 0.0f;
    out[NN * 4 + n * 12 + (row - 1) * 4 + g] = cb[row * 4 + g] * gate * 0.3f;
  }
}

extern "C" void kernel_launch(void* const* d_in, const int* in_sizes, int n_in,
                              void* d_out, int out_size, void* d_ws, size_t ws_size,
                              hipStream_t stream) {
  const float* positions = (const float*)d_in[0];
  const float* embed     = (const float*)d_in[1];
  const float* mpW       = (const float*)d_in[2];   // (3,3,3,3,8,32)
  const float* d1W       = (const float*)d_in[3];   // (3,3,32,32)
  const float* d1b       = (const float*)d_in[4];   // (3,32)
  const float* d2W       = (const float*)d_in[5];
  const float* d2b       = (const float*)d_in[6];
  const float* tdW       = (const float*)d_in[7];   // (3,3,2,32,4)
  const float* monoW     = (const float*)d_in[8];   // (4,4)
  const float* ebias     = (const float*)d_in[9];   // (18,)
  const int* Z   = (const int*)d_in[10];
  const int* dst = (const int*)d_in[11];
  const int* src = (const int*)d_in[12];
  float* out = (float*)d_out;

  float* Yb = (float*)d_ws;                 // NE*9  (dst-sorted)
  float* Rb = Yb + (size_t)NE * 9;          // NE*8  (dst-sorted)
  float* xb = Rb + (size_t)NE * 8;          // NN*288
  float* yb = xb + (size_t)NN * 288;        // NN*288
  int* ssrc = (int*)(yb + (size_t)NN * 288);  // NE  (dst-sorted src ids)
  int* sdst = ssrc + NE;                    // NE  (sorted dst ids)
  int* wofs = sdst + NE;                    // NN  (hist counters -> scatter cursors)

  gaunt_kernel<<<1, 768, 0, stream>>>();
  zero_kernel<<<(NN + 255) / 256, 256, 0, stream>>>(wofs);
  hist_kernel<<<NE / 256, 256, 0, stream>>>(dst, wofs);
  scan_kernel<<<1, 1024, 0, stream>>>(wofs);
  edge_kernel<<<NE / 256, 256, 0, stream>>>(positions, src, dst, wofs, ssrc, sdst, Yb, Rb);
  init_kernel<<<(NN * 288 + 255) / 256, 256, 0, stream>>>(embed, Z, xb);

  for (int it = 0; it < 3; ++it) {
    hipMemcpyAsync(yb, xb, (size_t)NN * 288 * sizeof(float), hipMemcpyDeviceToDevice, stream);
    message_kernel<<<NE / 8, 256, 0, stream>>>(xb, yb, Yb, Rb, mpW + (size_t)it * 27 * 256, ssrc, sdst);
    dense_kernel<<<NN, 288, 0, stream>>>(yb, xb, d1W + (size_t)it * 3 * 1024, d1b + it * 32,
                                         d2W + (size_t)it * 3 * 1024, d2b + it * 32);
  }
  final_kernel<<<NN, 128, 0, stream>>>(xb, tdW, monoW, ebias, Z, out);
}

// Round 3
// 587.107 us; speedup vs baseline: 1.8601x; 1.2645x over previous
//
#include <hip/hip_runtime.h>
#include <math.h>

#define NN 10000
#define NE 160000

namespace {
// MP_PATHS in reference order
constexpr int kL1[11] = {0,0,0,1,1,1,1,2,2,2,2};
constexpr int kL2[11] = {0,1,2,0,1,1,2,0,1,2,2};
constexpr int kL3[11] = {0,1,2,1,0,2,1,2,1,0,2};
// TD_PATHS in reference order
constexpr int tL1[7] = {0,0,1,1,1,2,2};
constexpr int tL2[7] = {0,1,0,1,2,1,2};
constexpr int tL3[7] = {0,1,1,0,1,1,0};
constexpr int kOFF[3] = {0,1,4};
constexpr int kWID[3] = {1,3,5};
}

__device__ float GAUNT_d[729];
__device__ unsigned char CT_P_d[115], CT_R_d[115], CT_L2_d[115];

// float32 spherical harmonics component (matches reference _sph_harm numerics)
__device__ __forceinline__ float sphf(int c, float x, float y, float z) {
  const float s3 = 1.7320508075688772f;
  switch (c) {
    case 0: return 1.0f;
    case 1: return x;
    case 2: return y;
    case 3: return z;
    case 4: return s3 * x * y;
    case 5: return s3 * y * z;
    case 6: return 0.5f * (3.0f * z * z - 1.0f);
    case 7: return s3 * x * z;
    default: return 0.5f * s3 * (x * x - y * y);
  }
}

// Gaunt table build: 16 double-trig calls total (staged in LDS), then a
// shared 128pt x 9comp Y table, then 729 threads do pure FMA loops.
__global__ void gaunt_kernel() {
  __shared__ float Ysh[128][9];
  __shared__ double cph[16], sph[16];
  __shared__ double stq[8], tsh[8], wsh[8];
  const int idx = threadIdx.x;
  const double T[8] = {-0.9602898564975363, -0.7966664774136267, -0.5255324099163290, -0.1834346424956498,
                        0.1834346424956498,  0.5255324099163290,  0.7966664774136267,  0.9602898564975363};
  const double Wq[8] = {0.1012285362903763, 0.2223810344533745, 0.3137066458778873, 0.3626837833783620,
                        0.3626837833783620, 0.3137066458778873, 0.2223810344533745, 0.1012285362903763};
  if (idx < 16) {
    double phi = (double)idx * (6.283185307179586 / 16.0);
    cph[idx] = cos(phi);
    sph[idx] = sin(phi);
  }
  if (idx < 8) {
    tsh[idx] = T[idx];
    wsh[idx] = Wq[idx] / 32.0;
    stq[idx] = sqrt(1.0 - T[idx] * T[idx]);
  }
  __syncthreads();
  for (int i = idx; i < 128 * 9; i += 768) {
    int k = i / 9, c = i - k * 9;
    int it = k >> 4, ip = k & 15;
    float xf = (float)(stq[it] * cph[ip]);
    float yf = (float)(stq[it] * sph[ip]);
    float zf = (float)tsh[it];
    Ysh[k][c] = sphf(c, xf, yf, zf);
  }
  __syncthreads();
  if (idx < 729) {
    int p = idx / 81, q = (idx / 9) % 9, r = idx % 9;
    double acc = 0.0;
    for (int k = 0; k < 128; ++k)  // same summation order as reference (it outer, ip inner)
      acc += wsh[k >> 4] * (double)Ysh[k][p] * (double)Ysh[k][q] * (double)Ysh[k][r];
    GAUNT_d[idx] = (fabs(acc) < 1e-10) ? 0.0f : (float)acc;
  }
  if (idx == 0) {
    // coef index -> (p_global, r_global, l2) tables, in (path, i, k) nesting order
    int c = 0;
    for (int t = 0; t < 11; ++t) {
      int l1 = kL1[t], l2 = kL2[t], l3 = kL3[t];
      for (int i = 0; i < kWID[l1]; ++i)
        for (int k = 0; k < kWID[l3]; ++k) {
          CT_P_d[c]  = (unsigned char)(kOFF[l1] + i);
          CT_R_d[c]  = (unsigned char)(kOFF[l3] + k);
          CT_L2_d[c] = (unsigned char)l2;
          ++c;
        }
    }
  }
}

// ---- destination-sorted edge order build ----
__global__ void zero_kernel(int* __restrict__ cnt) {
  int i = blockIdx.x * 256 + threadIdx.x;
  if (i < NN) cnt[i] = 0;
}

__global__ void hist_kernel(const int* __restrict__ dstI, int* __restrict__ cnt) {
  int e = blockIdx.x * 256 + threadIdx.x;
  if (e < NE) atomicAdd(&cnt[dstI[e]], 1);
}

// single-block in-place exclusive scan over wofs (counts -> start offsets)
__global__ void scan_kernel(int* __restrict__ wofs) {
  __shared__ int partial[1024];
  const int tid = threadIdx.x;           // 1024 threads, 10 elements each
  const int base = tid * 10;
  int local[10];
  int s = 0;
  #pragma unroll
  for (int i = 0; i < 10; ++i) {
    int idx = base + i;
    int v = (idx < NN) ? wofs[idx] : 0;
    local[i] = s;                        // exclusive within chunk
    s += v;
  }
  partial[tid] = s;
  __syncthreads();
  for (int off = 1; off < 1024; off <<= 1) {
    int v = (tid >= off) ? partial[tid - off] : 0;
    __syncthreads();
    partial[tid] += v;
    __syncthreads();
  }
  int pre = (tid == 0) ? 0 : partial[tid - 1];
  #pragma unroll
  for (int i = 0; i < 10; ++i) {
    int idx = base + i;
    if (idx < NN) wofs[idx] = pre + local[i];
  }
}

// edge basis, scattered directly into dst-sorted slot order
__global__ void edge_kernel(const float* __restrict__ pos,
                            const int* __restrict__ srcI, const int* __restrict__ dstI,
                            int* __restrict__ wofs, int* __restrict__ ssrc, int* __restrict__ sdst,
                            float* __restrict__ Yb, float* __restrict__ Rb) {
  int e = blockIdx.x * 256 + threadIdx.x;
  if (e >= NE) return;
  int s = srcI[e], d = dstI[e];
  float dx = pos[s * 3 + 0] - pos[d * 3 + 0];
  float dy = pos[s * 3 + 1] - pos[d * 3 + 1];
  float dz = pos[s * 3 + 2] - pos[d * 3 + 2];
  float r2 = dx * dx + dy * dy + dz * dz;
  float r = sqrtf(fmaxf(r2, 1e-12f));
  float inv = 1.0f / r;
  float x = dx * inv, y = dy * inv, z = dz * inv;
  const float s3 = 1.7320508075688772f;
  int sp = atomicAdd(&wofs[d], 1);       // dst-sorted slot
  ssrc[sp] = s;
  sdst[sp] = d;
  Yb[sp * 9 + 0] = 1.0f;
  Yb[sp * 9 + 1] = x;
  Yb[sp * 9 + 2] = y;
  Yb[sp * 9 + 3] = z;
  Yb[sp * 9 + 4] = s3 * x * y;
  Yb[sp * 9 + 5] = s3 * y * z;
  Yb[sp * 9 + 6] = 0.5f * (3.0f * z * z - 1.0f);
  Yb[sp * 9 + 7] = s3 * x * z;
  Yb[sp * 9 + 8] = 0.5f * s3 * (x * x - y * y);
  float rc = fminf(r, 5.0f - 1e-6f);
  float cut = (r < 5.0f) ? expf(-(rc * rc) / ((5.0f - rc) * (5.0f + rc))) : 0.0f;
  float yv = 1.0f / (1.0f + r);
  float om = 1.0f - yv;
  const float binom[8] = {1.f, 7.f, 21.f, 35.f, 35.f, 21.f, 7.f, 1.f};
  float yk[8], ok[8];
  yk[0] = 1.0f; ok[0] = 1.0f;
  #pragma unroll
  for (int k = 1; k < 8; ++k) { yk[k] = yk[k - 1] * yv; ok[k] = ok[k - 1] * om; }
  #pragma unroll
  for (int k = 0; k < 8; ++k) Rb[sp * 8 + k] = binom[k] * yk[k] * ok[7 - k] * cut;
}

__global__ void init_kernel(const float* __restrict__ embed, const int* __restrict__ Z,
                            float* __restrict__ xb) {
  int idx = blockIdx.x * 256 + threadIdx.x;
  if (idx >= NN * 288) return;
  int n = idx / 288;
  int rem = idx - n * 288;
  int p = rem >> 5, f = rem & 31;
  xb[idx] = (p == 0) ? embed[Z[n] * 32 + f] : 0.0f;
}

// edge-major message pass over dst-sorted edges; block-level segmented reduction
// cuts atomics from 1/edge-element to 1/(block,distinct-dst)-element (~5x fewer)
__launch_bounds__(256)
__global__ void message_kernel(const float* __restrict__ xb, float* __restrict__ yb,
                               const float* __restrict__ Yb, const float* __restrict__ Rb,
                               const float* __restrict__ Wg,
                               const int* __restrict__ ssrc, const int* __restrict__ sdst) {
  __shared__ float Gs[729];
  __shared__ float Ws[11 * 256];
  __shared__ float Ys[8][9];
  __shared__ float Rs[8][8];
  __shared__ float Cs[8][115];
  __shared__ float Ms[8][288];
  __shared__ int Ds[8];
  __shared__ int Hs[9];
  __shared__ int nseg_s;
  __shared__ unsigned char Tp[115], Tr[115], Tl2[115];
  const int tid = threadIdx.x;
  const int e0 = blockIdx.x * 8;

  for (int i = tid; i < 729; i += 256) Gs[i] = GAUNT_d[i];
  for (int i = tid; i < 115; i += 256) { Tp[i] = CT_P_d[i]; Tr[i] = CT_R_d[i]; Tl2[i] = CT_L2_d[i]; }
  #pragma unroll
  for (int t = 0; t < 11; ++t) {
    const int off = ((kL1[t] * 3 + kL2[t]) * 3 + kL3[t]) * 256;  // compile-time
    Ws[t * 256 + tid] = Wg[off + tid];
  }
  for (int i = tid; i < 128; i += 256) {
    int le = i >> 4, q = i & 15;
    if (q < 9) Ys[le][q] = Yb[(e0 + le) * 9 + q];
  }
  for (int i = tid; i < 64; i += 256) Rs[i >> 3][i & 7] = Rb[e0 * 8 + i];
  if (tid < 8) Ds[tid] = sdst[e0 + tid];
  __syncthreads();

  // cooperative per-edge coefficients: coef[c] = sum_q G[p, q, r] * Y[q]
  for (int i = tid; i < 1024; i += 256) {
    int le = i >> 7, c = i & 127;
    if (c < 115) {
      int p = Tp[c], r = Tr[c], l2 = Tl2[c];
      int q0 = (l2 == 0) ? 0 : ((l2 == 1) ? 1 : 4);
      int nq = (l2 == 0) ? 1 : ((l2 == 1) ? 3 : 5);
      float a = 0.0f;
      for (int j = 0; j < nq; ++j) a += Gs[(p * 9 + q0 + j) * 9 + r] * Ys[le][q0 + j];
      Cs[le][c] = a;
    }
  }
  if (tid == 0) {
    // segment heads among the 8 sorted edges
    int ns = 0;
    #pragma unroll
    for (int i = 0; i < 8; ++i)
      if (i == 0 || Ds[i] != Ds[i - 1]) Hs[ns++] = i;
    Hs[ns] = 8;
    nseg_s = ns;
  }
  __syncthreads();

  const int le = tid >> 5, f = tid & 31;
  const int sn = ssrc[e0 + le];

  float rw[11];
  #pragma unroll
  for (int t = 0; t < 11; ++t) {
    float a = 0.0f;
    #pragma unroll
    for (int k = 0; k < 8; ++k) a += Rs[le][k] * Ws[t * 256 + k * 32 + f];
    rw[t] = a;
  }
  float xs[9];
  #pragma unroll
  for (int p = 0; p < 9; ++p) xs[p] = xb[sn * 288 + p * 32 + f];

  float msg[9] = {0.f, 0.f, 0.f, 0.f, 0.f, 0.f, 0.f, 0.f, 0.f};
  int c = 0;
  #pragma unroll
  for (int t = 0; t < 11; ++t) {
    const int o1 = kOFF[kL1[t]], w1 = kWID[kL1[t]];
    const int o3 = kOFF[kL3[t]], w3 = kWID[kL3[t]];
    #pragma unroll
    for (int i = 0; i < w1; ++i) {
      float tv = rw[t] * xs[o1 + i];
      #pragma unroll
      for (int k = 0; k < w3; ++k) { msg[o3 + k] += Cs[le][c] * tv; ++c; }
    }
  }
  #pragma unroll
  for (int rr = 0; rr < 9; ++rr) Ms[le][rr * 32 + f] = msg[rr];
  __syncthreads();

  // segmented reduction over the (sorted) 8 edges; one atomic per segment-element
  const int nseg = nseg_s;
  for (int i = tid; i < nseg * 288; i += 256) {
    int s = i / 288, rf = i - s * 288;
    int h = Hs[s], hend = Hs[s + 1];
    float a = 0.0f;
    for (int e = h; e < hend; ++e) a += Ms[e][rf];
    atomicAdd(&yb[Ds[h] * 288 + rf], a);
  }
}

// fused dense1 + silu_e3 + dense2 + residual, one block per node
__global__ void dense_kernel(const float* __restrict__ ybuf, float* __restrict__ xb,
                             const float* __restrict__ W1, const float* __restrict__ b1,
                             const float* __restrict__ W2, const float* __restrict__ b2) {
  __shared__ float yn[288];
  __shared__ float act[288];
  __shared__ float sb[32];
  const int n = blockIdx.x;
  const int tid = threadIdx.x;  // p*32+g, 288 threads
  const int p = tid >> 5, g = tid & 31;
  yn[tid] = ybuf[n * 288 + tid];
  __syncthreads();
  const int dg = (p == 0) ? 0 : ((p < 4) ? 1 : 2);
  float a = (p == 0) ? b1[g] : 0.0f;
  #pragma unroll
  for (int f = 0; f < 32; ++f) a += yn[p * 32 + f] * W1[(dg * 32 + f) * 32 + g];
  if (p == 0) sb[g] = a;
  __syncthreads();
  float s = sb[g];
  float sg = 1.0f / (1.0f + expf(-s));
  float v = (p == 0) ? s * sg : a * (sg * (1.0f + s * (1.0f - sg)));
  act[tid] = v;
  __syncthreads();
  float o = (p == 0) ? b2[g] : 0.0f;
  #pragma unroll
  for (int f = 0; f < 32; ++f) o += act[p * 32 + f] * W2[(dg * 32 + f) * 32 + g];
  xb[n * 288 + tid] += o;
}

// tensor_dense + mono/dipo outputs, one block (128 thr) per node; tid = r*32+f, r in 0..3
__global__ void final_kernel(const float* __restrict__ xb, const float* __restrict__ tdW,
                             const float* __restrict__ monoW, const float* __restrict__ ebias,
                             const int* __restrict__ Z, float* __restrict__ out) {
  __shared__ float xl[288];
  __shared__ float B[4][32];
  __shared__ float cb[16];
  const int n = blockIdx.x;
  const int tid = threadIdx.x;
  const int r = tid >> 5, f = tid & 31;
  for (int i = tid; i < 288; i += 128) xl[i] = xb[n * 288 + i];
  __syncthreads();
  float creg = 0.0f;  // c[r][g=f] accumulator, valid on f<4 threads
  #pragma unroll
  for (int t = 0; t < 7; ++t) {
    const int l1 = tL1[t], l2 = tL2[t], l3 = tL3[t];
    const bool active = (l3 == 0) ? (r == 0) : (r >= 1);
    float b = 0.0f;
    if (active) {
      #pragma unroll
      for (int i = 0; i < kWID[l1]; ++i) {
        const int p = kOFF[l1] + i;
        float xp = xl[p * 32 + f];
        #pragma unroll
        for (int j = 0; j < kWID[l2]; ++j) {
          const int q = kOFF[l2] + j;
          b += GAUNT_d[(p * 9 + q) * 9 + r] * xp * xl[q * 32 + f];
        }
      }
    }
    B[r][f] = b;
    __syncthreads();
    if (f < 4 && active) {
      const float* w = tdW + ((l1 * 3 + l2) * 2 + l3) * 128;
      float acc = 0.0f;
      #pragma unroll
      for (int f2 = 0; f2 < 32; ++f2) acc += B[r][f2] * w[f2 * 4 + f];
      creg += acc;
    }
    __syncthreads();
  }
  if (f < 4) cb[r * 4 + f] = creg;
  __syncthreads();
  if (tid < 4) {
    int g = tid;
    float m = 0.0f;
    #pragma unroll
    for (int j = 0; j < 4; ++j) m += cb[j] * monoW[j * 4 + g];
    out[n * 4 + g] = m + ebias[Z[n]];
  }
  if (tid < 12) {
    int row = tid / 4 + 1, g = tid % 4;
    float s = cb[g];
    float gate = (s > -1.0f && s < 1.0f) ? 1.0f : 0.0f;
    out[NN * 4 + n * 12 + (row - 1) * 4 + g] = cb[row * 4 + g] * gate * 0.3f;
  }
}

extern "C" void kernel_launch(void* const* d_in, const int* in_sizes, int n_in,
                              void* d_out, int out_size, void* d_ws, size_t ws_size,
                              hipStream_t stream) {
  const float* positions = (const float*)d_in[0];
  const float* embed     = (const float*)d_in[1];
  const float* mpW       = (const float*)d_in[2];   // (3,3,3,3,8,32)
  const float* d1W       = (const float*)d_in[3];   // (3,3,32,32)
  const float* d1b       = (const float*)d_in[4];   // (3,32)
  const float* d2W       = (const float*)d_in[5];
  const float* d2b       = (const float*)d_in[6];
  const float* tdW       = (const float*)d_in[7];   // (3,3,2,32,4)
  const float* monoW     = (const float*)d_in[8];   // (4,4)
  const float* ebias     = (const float*)d_in[9];   // (18,)
  const int* Z   = (const int*)d_in[10];
  const int* dst = (const int*)d_in[11];
  const int* src = (const int*)d_in[12];
  float* out = (float*)d_out;

  float* Yb = (float*)d_ws;                 // NE*9  (dst-sorted)
  float* Rb = Yb + (size_t)NE * 9;          // NE*8  (dst-sorted)
  float* xb = Rb + (size_t)NE * 8;          // NN*288
  float* yb = xb + (size_t)NN * 288;        // NN*288
  int* ssrc = (int*)(yb + (size_t)NN * 288);  // NE  (dst-sorted src ids)
  int* sdst = ssrc + NE;                    // NE  (sorted dst ids)
  int* wofs = sdst + NE;                    // NN  (hist counters -> scatter cursors)

  gaunt_kernel<<<1, 768, 0, stream>>>();
  zero_kernel<<<(NN + 255) / 256, 256, 0, stream>>>(wofs);
  hist_kernel<<<NE / 256, 256, 0, stream>>>(dst, wofs);
  scan_kernel<<<1, 1024, 0, stream>>>(wofs);
  edge_kernel<<<NE / 256, 256, 0, stream>>>(positions, src, dst, wofs, ssrc, sdst, Yb, Rb);
  init_kernel<<<(NN * 288 + 255) / 256, 256, 0, stream>>>(embed, Z, xb);

  for (int it = 0; it < 3; ++it) {
    hipMemcpyAsync(yb, xb, (size_t)NN * 288 * sizeof(float), hipMemcpyDeviceToDevice, stream);
    message_kernel<<<NE / 8, 256, 0, stream>>>(xb, yb, Yb, Rb, mpW + (size_t)it * 27 * 256, ssrc, sdst);
    dense_kernel<<<NN, 288, 0, stream>>>(yb, xb, d1W + (size_t)it * 3 * 1024, d1b + it * 32,
                                         d2W + (size_t)it * 3 * 1024, d2b + it * 32);
  }
  final_kernel<<<NN, 128, 0, stream>>>(xb, tdW, monoW, ebias, Z, out);
}